// Round 1
// baseline (33450.375 us; speedup 1.0000x reference)
//
#include <hip/hip_runtime.h>

// APDL_RNN: allpass-delay LSTM. B=32, T=8192, I=1, H=256, OS_FACTOR=1.5 -> coeff=1/3.
// Decomposition: 128 WGs = 32 batches x 4 quartet members. Each WG owns 64 hidden
// units (256 gate rows); each thread owns ONE gate row with its 256 fp32 weights
// register-resident (1 wave/SIMD => 512 VGPR budget). Per step the quartet
// all-gathers the 256-dim allpass-filtered h through an agent-coherent buffer in
// d_ws with per-WG monotonic flags (parity double-buffered, race-free).

#define Bn 32
#define Tn 8192
#define Hn 256

static constexpr float kCoeff = 1.0f / 3.0f;  // (1-alpha)/(1+alpha), alpha=0.5

__device__ __forceinline__ float sigf(float x) {
  return __builtin_amdgcn_rcpf(1.0f + __expf(-x));
}
__device__ __forceinline__ float tanhf_fast(float x) {
  // tanh(x) = 1 - 2/(exp(2x)+1)
  return 1.0f - 2.0f * __builtin_amdgcn_rcpf(1.0f + __expf(2.0f * x));
}
// value at shuffle-distance d within the 4-lane gate group
__device__ __forceinline__ float pick4(int d, float v0, float v1, float v2, float v3) {
  float r = (d == 0) ? v0 : v1;
  r = (d == 2) ? v2 : r;
  r = (d == 3) ? v3 : r;
  return r;
}

// d_ws layout: int flags[32][4] (each padded to 16 ints = 64B)  -> 8192 bytes
//              float pub[32][2][256]                            -> 65536 bytes
__global__ void init_ws(int* ws) {
  int i = blockIdx.x * 256 + threadIdx.x;
  if (i < 18432) ws[i] = 0;
}

__global__ __launch_bounds__(256, 1) void apdl_rnn(
    const float* __restrict__ x, const float* __restrict__ W_ih,
    const float* __restrict__ W_hh, const float* __restrict__ b_ih,
    const float* __restrict__ b_hh, float* __restrict__ out,
    int* __restrict__ flags, float* __restrict__ pub) {
  const int bid = blockIdx.x;
  const int w = bid >> 5;   // quartet member 0..3 (blocks b, b+32, b+64, b+96 -> same XCD)
  const int b = bid & 31;   // batch
  const int tid = (int)threadIdx.x;
  const int g = tid & 3;    // gate: 0=i 1=f 2=g 3=o
  const int ul = tid >> 2;  // local hidden unit 0..63
  const int u = w * 64 + ul;      // global hidden unit 0..255
  const int row = g * Hn + u;     // gate row 0..1023

  __shared__ __align__(16) float xs[Tn];  // this batch's x sequence, 32KB
  __shared__ __align__(16) float hs[Hn];  // current step's ap_h (matmul input)

  // one-time: stage x[b][*] into LDS (covered by first __syncthreads below)
  for (int i = tid; i < Tn; i += 256) xs[i] = x[b * Tn + i];

  // one-time: this thread's W_hh row into registers (256 VGPRs)
  float wreg[Hn];
  {
    const float* wrow = W_hh + row * Hn;
#pragma unroll
    for (int k = 0; k < Hn; k += 4) {
      float4 v = *(const float4*)(wrow + k);
      wreg[k] = v.x; wreg[k + 1] = v.y; wreg[k + 2] = v.z; wreg[k + 3] = v.w;
    }
  }
  const float wih = W_ih[row];
  const float bias = b_ih[row] + b_hh[row];

  int* myflags = flags + b * 4 * 16;      // [v]*16
  float* mypub = pub + b * 2 * 256;       // [parity]*256 + unit

  // per-unit recurrent state, replicated across the 4 gate lanes
  float s1_h = 0.f, s1_c = 0.f, ap_h = 0.f, ap_c = 0.f;

  for (int t = 0; t < Tn; ++t) {
    // ---- acquire ap_h(t) for all 256 hidden units into LDS ----
    if (t == 0) {
      hs[tid] = 0.f;  // ap(0) = 0
    } else {
#pragma unroll
      for (int v = 0; v < 4; ++v) {
        while (__hip_atomic_load(myflags + v * 16, __ATOMIC_RELAXED,
                                 __HIP_MEMORY_SCOPE_AGENT) < t) { }
      }
      // coherent (agent-scope) load; thread tid fetches element tid, coalesced
      hs[tid] = __hip_atomic_load(mypub + (t & 1) * 256 + tid, __ATOMIC_RELAXED,
                                  __HIP_MEMORY_SCOPE_AGENT);
    }
    __syncthreads();

    // ---- gate dot product: wreg . hs (256 fp32 MACs, 8 accumulators) ----
    float a0 = 0.f, a1 = 0.f, a2 = 0.f, a3 = 0.f, a4 = 0.f, a5 = 0.f, a6 = 0.f, a7 = 0.f;
#pragma unroll
    for (int k = 0; k < Hn; k += 8) {
      float4 p = *(const float4*)&hs[k];
      float4 q = *(const float4*)&hs[k + 4];
      a0 = fmaf(wreg[k + 0], p.x, a0);
      a1 = fmaf(wreg[k + 1], p.y, a1);
      a2 = fmaf(wreg[k + 2], p.z, a2);
      a3 = fmaf(wreg[k + 3], p.w, a3);
      a4 = fmaf(wreg[k + 4], q.x, a4);
      a5 = fmaf(wreg[k + 5], q.y, a5);
      a6 = fmaf(wreg[k + 6], q.z, a6);
      a7 = fmaf(wreg[k + 7], q.w, a7);
    }
    float dot = ((a0 + a1) + (a2 + a3)) + ((a4 + a5) + (a6 + a7));
    float raw = dot + xs[t] * wih + bias;

    // ---- activate own gate, then exchange within the 4-lane unit group ----
    float act = (g == 2) ? tanhf_fast(raw) : sigf(raw);
    float v1 = __shfl_xor(act, 1);
    float v2 = __shfl_xor(act, 2);
    float v3 = __shfl_xor(act, 3);
    float ai = pick4(g,     act, v1, v2, v3);  // sigmoid(i)
    float af = pick4(g ^ 1, act, v1, v2, v3);  // sigmoid(f)
    float ag = pick4(g ^ 2, act, v1, v2, v3);  // tanh(g)
    float ao = pick4(g ^ 3, act, v1, v2, v3);  // sigmoid(o)

    float c_new = af * ap_c + ai * ag;
    float h_new = ao * tanhf_fast(c_new);

    // ---- outputs: (y, h, c) all fp32 ----
    int o = (b * Tn + t) * Hn + u;
    if (g == 0)      out[o] = h_new;                 // y
    else if (g == 2) out[67108864 + o] = h_new;      // states h
    else if (g == 1) out[134217728 + o] = c_new;     // states c

    if (t < Tn - 1) {
      // ---- allpass update: ap(t+1) = coeff*(s(t)-ap(t)) + s(t-1) ----
      float nh = kCoeff * (h_new - ap_h) + s1_h;
      float nc = kCoeff * (c_new - ap_c) + s1_c;
      s1_h = h_new; s1_c = c_new; ap_h = nh; ap_c = nc;
      // publish our 64-unit ap_h slice for step t+1 (agent-coherent)
      if (g == 3)
        __hip_atomic_store(mypub + ((t + 1) & 1) * 256 + u, nh, __ATOMIC_RELAXED,
                           __HIP_MEMORY_SCOPE_AGENT);
      asm volatile("s_waitcnt vmcnt(0)" ::: "memory");  // drain own stores
      __syncthreads();                                   // all lanes' stores done
      if (tid == 0)
        __hip_atomic_store(myflags + w * 16, t + 1, __ATOMIC_RELAXED,
                           __HIP_MEMORY_SCOPE_AGENT);
    } else {
      // ap_final = ap used in the last step
      if (g == 0)      out[201326592 + b * 512 + u] = ap_h;
      else if (g == 1) out[201326592 + b * 512 + 256 + u] = ap_c;
    }
  }
}

extern "C" void kernel_launch(void* const* d_in, const int* in_sizes, int n_in,
                              void* d_out, int out_size, void* d_ws, size_t ws_size,
                              hipStream_t stream) {
  const float* x = (const float*)d_in[0];
  const float* W_ih = (const float*)d_in[1];
  const float* W_hh = (const float*)d_in[2];
  const float* b_ih = (const float*)d_in[3];
  const float* b_hh = (const float*)d_in[4];
  float* out = (float*)d_out;
  int* flags = (int*)d_ws;
  float* pub = (float*)((char*)d_ws + 8192);

  init_ws<<<72, 256, 0, stream>>>((int*)d_ws);  // reset flags+pub every launch
  apdl_rnn<<<128, 256, 0, stream>>>(x, W_ih, W_hh, b_ih, b_hh, out, flags, pub);
}

// Round 2
// 33206.403 us; speedup vs baseline: 1.0073x; 1.0073x over previous
//
#include <hip/hip_runtime.h>

// APDL_RNN: allpass-delay LSTM. B=32, T=8192, I=1, H=256, OS_FACTOR=1.5 -> coeff=1/3.
// 128 WGs = 32 batches x 4 quartet members. Each WG owns 64 hidden units (256 gate
// rows); each thread owns ONE gate row with its 256 fp32 weights in REGISTERS via
// 16x floatx16 SSA values (R1's float[256] array spilled to scratch: VGPR=148).
// 1 wave/SIMD (__launch_bounds__(256,1)) gives the 512-VGPR budget.
// Per step the quartet all-gathers the 256-dim allpass-filtered h through an
// agent-coherent buffer in d_ws with per-WG monotonic flags (parity dbuf).

#define Bn 32
#define Tn 8192
#define Hn 256

typedef float floatx16 __attribute__((ext_vector_type(16)));

static constexpr float kCoeff = 1.0f / 3.0f;  // (1-alpha)/(1+alpha), alpha=0.5

__device__ __forceinline__ float sigf(float x) {
  return __builtin_amdgcn_rcpf(1.0f + __expf(-x));
}
__device__ __forceinline__ float tanhf_fast(float x) {
  return 1.0f - 2.0f * __builtin_amdgcn_rcpf(1.0f + __expf(2.0f * x));
}
__device__ __forceinline__ float pick4(int d, float v0, float v1, float v2, float v3) {
  float r = (d == 0) ? v0 : v1;
  r = (d == 2) ? v2 : r;
  r = (d == 3) ? v3 : r;
  return r;
}

// d_ws layout: int flags[32][4] (each padded to 16 ints = 64B)  -> 8192 bytes
//              float pub[32][2][256]                            -> 65536 bytes
__global__ void init_ws(int* ws) {
  int i = blockIdx.x * 256 + threadIdx.x;
  if (i < 18432) ws[i] = 0;
}

// 16 fp32 FMAs into 8 accumulators; hs reads are wave-uniform (LDS broadcast).
#define ACC16(WV, K)                                         \
  {                                                          \
    float4 p = *(const float4*)&hs[(K) + 0];                 \
    float4 q = *(const float4*)&hs[(K) + 4];                 \
    float4 r2 = *(const float4*)&hs[(K) + 8];                \
    float4 s2 = *(const float4*)&hs[(K) + 12];               \
    a0 = fmaf(WV[0], p.x, a0);   a1 = fmaf(WV[1], p.y, a1);  \
    a2 = fmaf(WV[2], p.z, a2);   a3 = fmaf(WV[3], p.w, a3);  \
    a4 = fmaf(WV[4], q.x, a4);   a5 = fmaf(WV[5], q.y, a5);  \
    a6 = fmaf(WV[6], q.z, a6);   a7 = fmaf(WV[7], q.w, a7);  \
    a0 = fmaf(WV[8], r2.x, a0);  a1 = fmaf(WV[9], r2.y, a1); \
    a2 = fmaf(WV[10], r2.z, a2); a3 = fmaf(WV[11], r2.w, a3);\
    a4 = fmaf(WV[12], s2.x, a4); a5 = fmaf(WV[13], s2.y, a5);\
    a6 = fmaf(WV[14], s2.z, a6); a7 = fmaf(WV[15], s2.w, a7);\
  }

__global__ __launch_bounds__(256, 1) void apdl_rnn(
    const float* __restrict__ x, const float* __restrict__ W_ih,
    const float* __restrict__ W_hh, const float* __restrict__ b_ih,
    const float* __restrict__ b_hh, float* __restrict__ out,
    int* __restrict__ flags, float* __restrict__ pub) {
  const int bid = blockIdx.x;
  const int w = bid >> 5;   // quartet member 0..3 (blocks b, b+32, ... -> same XCD)
  const int b = bid & 31;   // batch
  const int tid = (int)threadIdx.x;
  const int g = tid & 3;    // gate: 0=i 1=f 2=g 3=o
  const int ul = tid >> 2;  // local hidden unit 0..63
  const int u = w * 64 + ul;      // global hidden unit 0..255
  const int row = g * Hn + u;     // gate row 0..1023

  __shared__ __align__(16) float xs[Tn];  // this batch's x sequence, 32KB
  __shared__ __align__(16) float hs[Hn];  // current step's ap_h (matmul input)

  for (int i = tid; i < Tn; i += 256) xs[i] = x[b * Tn + i];

  // this thread's W_hh row: 16 x floatx16 SSA values -> guaranteed VGPRs
  const float* wrow = W_hh + row * Hn;
  floatx16 w0  = *(const floatx16*)(wrow + 0 * 16);
  floatx16 w1  = *(const floatx16*)(wrow + 1 * 16);
  floatx16 w2  = *(const floatx16*)(wrow + 2 * 16);
  floatx16 w3  = *(const floatx16*)(wrow + 3 * 16);
  floatx16 w4  = *(const floatx16*)(wrow + 4 * 16);
  floatx16 w5  = *(const floatx16*)(wrow + 5 * 16);
  floatx16 w6  = *(const floatx16*)(wrow + 6 * 16);
  floatx16 w7  = *(const floatx16*)(wrow + 7 * 16);
  floatx16 w8  = *(const floatx16*)(wrow + 8 * 16);
  floatx16 w9  = *(const floatx16*)(wrow + 9 * 16);
  floatx16 w10 = *(const floatx16*)(wrow + 10 * 16);
  floatx16 w11 = *(const floatx16*)(wrow + 11 * 16);
  floatx16 w12 = *(const floatx16*)(wrow + 12 * 16);
  floatx16 w13 = *(const floatx16*)(wrow + 13 * 16);
  floatx16 w14 = *(const floatx16*)(wrow + 14 * 16);
  floatx16 w15 = *(const floatx16*)(wrow + 15 * 16);

  const float wih = W_ih[row];
  const float bias = b_ih[row] + b_hh[row];

  int* myflags = flags + b * 4 * 16;   // [v]*16 ints
  float* mypub = pub + b * 2 * 256;    // [parity]*256 + unit

  float s1_h = 0.f, s1_c = 0.f, ap_h = 0.f, ap_c = 0.f;

  for (int t = 0; t < Tn; ++t) {
    // ---- acquire ap_h(t) for all 256 hidden units into LDS ----
    if (t == 0) {
      hs[tid] = 0.f;  // ap(0) = 0
    } else {
#pragma unroll
      for (int v = 0; v < 4; ++v) {
        while (__hip_atomic_load(myflags + v * 16, __ATOMIC_RELAXED,
                                 __HIP_MEMORY_SCOPE_AGENT) < t) { }
      }
      hs[tid] = __hip_atomic_load(mypub + (t & 1) * 256 + tid, __ATOMIC_RELAXED,
                                  __HIP_MEMORY_SCOPE_AGENT);
    }
    __syncthreads();

    // ---- gate dot product: 256 fp32 MACs, weights in VGPRs ----
    float a0 = 0.f, a1 = 0.f, a2 = 0.f, a3 = 0.f;
    float a4 = 0.f, a5 = 0.f, a6 = 0.f, a7 = 0.f;
    ACC16(w0, 0);    ACC16(w1, 16);   ACC16(w2, 32);   ACC16(w3, 48);
    ACC16(w4, 64);   ACC16(w5, 80);   ACC16(w6, 96);   ACC16(w7, 112);
    ACC16(w8, 128);  ACC16(w9, 144);  ACC16(w10, 160); ACC16(w11, 176);
    ACC16(w12, 192); ACC16(w13, 208); ACC16(w14, 224); ACC16(w15, 240);
    float dot = ((a0 + a1) + (a2 + a3)) + ((a4 + a5) + (a6 + a7));
    float raw = dot + xs[t] * wih + bias;

    // ---- activate own gate, exchange within the 4-lane unit group ----
    float act = (g == 2) ? tanhf_fast(raw) : sigf(raw);
    float v1 = __shfl_xor(act, 1);
    float v2 = __shfl_xor(act, 2);
    float v3 = __shfl_xor(act, 3);
    float ai = pick4(g,     act, v1, v2, v3);  // sigmoid(i)
    float af = pick4(g ^ 1, act, v1, v2, v3);  // sigmoid(f)
    float ag = pick4(g ^ 2, act, v1, v2, v3);  // tanh(g)
    float ao = pick4(g ^ 3, act, v1, v2, v3);  // sigmoid(o)

    float c_new = af * ap_c + ai * ag;
    float h_new = ao * tanhf_fast(c_new);

    // ---- outputs: (y, states_h, states_c) fp32 ----
    int o = (b * Tn + t) * Hn + u;
    if (g == 0)      out[o] = h_new;                 // y
    else if (g == 2) out[67108864 + o] = h_new;      // states h
    else if (g == 1) out[134217728 + o] = c_new;     // states c

    if (t < Tn - 1) {
      // ---- allpass update: ap(t+1) = coeff*(s(t)-ap(t)) + s(t-1) ----
      float nh = kCoeff * (h_new - ap_h) + s1_h;
      float nc = kCoeff * (c_new - ap_c) + s1_c;
      s1_h = h_new; s1_c = c_new; ap_h = nh; ap_c = nc;
      if (g == 3)
        __hip_atomic_store(mypub + ((t + 1) & 1) * 256 + u, nh, __ATOMIC_RELAXED,
                           __HIP_MEMORY_SCOPE_AGENT);
      asm volatile("s_waitcnt vmcnt(0)" ::: "memory");  // drain own pub stores
      __syncthreads();                                   // all lanes drained
      if (tid == 0)
        __hip_atomic_store(myflags + w * 16, t + 1, __ATOMIC_RELAXED,
                           __HIP_MEMORY_SCOPE_AGENT);
    } else {
      if (g == 0)      out[201326592 + b * 512 + u] = ap_h;        // ap_final h
      else if (g == 1) out[201326592 + b * 512 + 256 + u] = ap_c;  // ap_final c
    }
  }
}

extern "C" void kernel_launch(void* const* d_in, const int* in_sizes, int n_in,
                              void* d_out, int out_size, void* d_ws, size_t ws_size,
                              hipStream_t stream) {
  const float* x = (const float*)d_in[0];
  const float* W_ih = (const float*)d_in[1];
  const float* W_hh = (const float*)d_in[2];
  const float* b_ih = (const float*)d_in[3];
  const float* b_hh = (const float*)d_in[4];
  float* out = (float*)d_out;
  int* flags = (int*)d_ws;
  float* pub = (float*)((char*)d_ws + 8192);

  init_ws<<<72, 256, 0, stream>>>((int*)d_ws);  // reset flags+pub every launch
  apdl_rnn<<<128, 256, 0, stream>>>(x, W_ih, W_hh, b_ih, b_hh, out, flags, pub);
}